// Round 6
// baseline (7039.292 us; speedup 1.0000x reference)
//
#include <hip/hip_runtime.h>

typedef short s16x8 __attribute__((ext_vector_type(8)));   // 8 bf16 as raw bits (guide §3)
typedef float f32x4 __attribute__((ext_vector_type(4)));
typedef unsigned short u16;

__device__ __forceinline__ u16 f2bf(float x){
    unsigned u = __float_as_uint(x);
    unsigned r = u + 0x7fffu + ((u >> 16) & 1u);
    return (u16)(r >> 16);
}

// ---------------- ROI align (fp32 in, bf16 out): rbuf[(f*6+b)*9+sp][1024]; row 1728 = 0 ----
__global__ __launch_bounds__(256) void roi_kernel(const float* __restrict__ fmaps,
                                                  const float* __restrict__ boxes,
                                                  u16* __restrict__ rbuf){
    int blk = blockIdx.x;              // 0..1728 ; 1728 is the zero row
    u16* dst = rbuf + (size_t)blk * 1024;
    if (blk == 1728){
        for (int c = threadIdx.x; c < 1024; c += blockDim.x) dst[c] = 0;
        return;
    }
    int f = blk / 54; int r = blk % 54; int b = r / 9; int sp = r % 9;
    int oh = sp / 3, ow = sp % 3;
    const float* bx = boxes + (f * 6 + b) * 4;
    float x1 = bx[0], y1 = bx[1], x2 = bx[2], y2 = bx[3];
    float bw = fmaxf(x2 - x1, 1.0f) * (1.0f / 3.0f);
    float bh = fmaxf(y2 - y1, 1.0f) * (1.0f / 3.0f);
    int iy0[2], iy1[2], ix0[2], ix1[2];
    float ly[2], lx[2];
#pragma unroll
    for (int s = 0; s < 2; ++s){
        float gy = (float)oh + (s + 0.5f) * 0.5f;
        float ys = y1 + bh * gy;
        float y0f = floorf(ys); y0f = fminf(fmaxf(y0f, 0.f), 13.f);
        ly[s] = fminf(fmaxf(ys - y0f, 0.f), 1.f);
        iy0[s] = (int)y0f; iy1[s] = min(iy0[s] + 1, 13);
        float gx = (float)ow + (s + 0.5f) * 0.5f;
        float xs = x1 + bw * gx;
        float x0f = floorf(xs); x0f = fminf(fmaxf(x0f, 0.f), 13.f);
        lx[s] = fminf(fmaxf(xs - x0f, 0.f), 1.f);
        ix0[s] = (int)x0f; ix1[s] = min(ix0[s] + 1, 13);
    }
    int offs[16]; float wts[16]; int idx = 0;
#pragma unroll
    for (int sy = 0; sy < 2; ++sy)
#pragma unroll
        for (int sx = 0; sx < 2; ++sx){
            float wy1v = ly[sy], wy0v = 1.f - wy1v;
            float wx1v = lx[sx], wx0v = 1.f - wx1v;
            offs[idx] = iy0[sy] * 14 + ix0[sx]; wts[idx] = wy0v * wx0v; idx++;
            offs[idx] = iy0[sy] * 14 + ix1[sx]; wts[idx] = wy0v * wx1v; idx++;
            offs[idx] = iy1[sy] * 14 + ix0[sx]; wts[idx] = wy1v * wx0v; idx++;
            offs[idx] = iy1[sy] * 14 + ix1[sx]; wts[idx] = wy1v * wx1v; idx++;
        }
    const float* fb0 = fmaps + (size_t)f * 1024 * 196;
    for (int c = threadIdx.x; c < 1024; c += blockDim.x){
        const float* fm = fb0 + (size_t)c * 196;
        float acc = 0.f;
#pragma unroll
        for (int i = 0; i < 16; ++i) acc += fm[offs[i]] * wts[i];
        dst[c] = f2bf(acc * 0.25f);
    }
}

// ---------------- rowidx[fb][t] = rbuf row base (r*9) of matched person, or -1 ------------
__global__ void rowidx_kernel(const int* __restrict__ pid, int* __restrict__ rowidx){
    int i = blockIdx.x * blockDim.x + threadIdx.x;   // 960 = 192*5
    if (i >= 960) return;
    int fb = i / 5, t = i % 5;
    int f = fb / 6, b = fb % 6;
    int start = max(f - 2, 0);
    int end = min(start + 4, 31);
    int span = end - start;
    int g = start + (t * span) / 4;      // == trunc(float(t)*span/4) for these ranges
    int p = pid[f * 6 + b];
    int r = -1;
#pragma unroll
    for (int j = 0; j < 6; ++j)
        if (pid[g * 6 + j] == p){ r = (g * 6 + j) * 9; break; }
    rowidx[i] = r;
}

// ---------------- GEMM1: conv1a, TAP-MAJOR K (k = tap*1024 + ic) --------------------------
#define KP2 40   // LDS row stride in u16 (80 B); 16B-aligned ds_read_b128

__global__ __launch_bounds__(256) void gemm1_kernel(
        const float* __restrict__ w1,    // [512][1024][27] fp32 native (oc, ic, tap)
        const u16* __restrict__ rb,      // [1729][1024] bf16 ROI features (row 1728 = 0)
        const int* __restrict__ rowidx,  // [192][5]
        const float* __restrict__ bias,  // [512] fp32
        u16* __restrict__ y)             // [8640][512] channel-last bf16
{
    __shared__ u16 As[128 * KP2];
    __shared__ u16 Bs[128 * KP2];
    const int tid = threadIdx.x;
    const int m0 = blockIdx.x * 128;
    const int n0 = blockIdx.y * 128;
    const int row = tid >> 2, seg = tid & 3;

    const float* arow0 = w1 + (size_t)(m0 + row) * 27648;
    const float* arow1 = arow0 + (size_t)64 * 27648;

    // decode the two n-rows this thread stages; per-kd matched rbuf row base
    bool valid[2]; int ohv[2], owv[2]; int rkd[2][3];
#pragma unroll
    for (int e = 0; e < 2; ++e){
        int nr = n0 + row + e * 64;
        valid[e] = nr < 8640;
        int n = valid[e] ? nr : 0;
        int fb = n / 45, r = n % 45;
        int od = r / 9; ohv[e] = (r % 9) / 3; owv[e] = r % 3;
#pragma unroll
        for (int kd = 0; kd < 3; ++kd){
            int t = od + kd - 1;
            rkd[e][kd] = (t >= 0 && t <= 4) ? rowidx[fb * 5 + t] : -1;
        }
    }

    const int lane = tid & 63, wv = tid >> 6;
    const int wm = (wv & 1) * 64, wn = (wv >> 1) * 64;
    const int lid = lane & 15, q = lane >> 4;
    f32x4 acc[4][4];
#pragma unroll
    for (int i = 0; i < 4; ++i)
#pragma unroll
        for (int j = 0; j < 4; ++j) acc[i][j] = (f32x4){0.f, 0.f, 0.f, 0.f};

    for (int tap = 0; tap < 27; ++tap){
        const int kd = tap / 9, tr = tap % 9;
        const int kh = tr / 3,  kw = tr % 3;
        // B source row for this tap (1728 = zero row)
        int brow[2];
#pragma unroll
        for (int e = 0; e < 2; ++e){
            int h = ohv[e] + kh - 1, w = owv[e] + kw - 1;
            int rbase = rkd[e][kd];
            bool ok = valid[e] && rbase >= 0 && (unsigned)h < 3u && (unsigned)w < 3u;
            brow[e] = ok ? (rbase + h * 3 + w) : 1728;
        }
        const u16* bp0 = rb + ((size_t)brow[0] << 10) + seg * 8;
        const u16* bp1 = rb + ((size_t)brow[1] << 10) + seg * 8;
        const float* pa0 = arow0 + tap;
        const float* pa1 = arow1 + tap;

        for (int kc = 0; kc < 32; ++kc){
            const int icb = kc * 32 + seg * 8;     // ic base for this thread's 8 columns
            // A: 8 stride-27 fp32 loads per row, packed to bf16
            uint4 a0, a1;
            {
                const float* p0 = pa0 + (size_t)icb * 27;
                const float* p1 = pa1 + (size_t)icb * 27;
                a0.x = (unsigned)f2bf(p0[0])      | ((unsigned)f2bf(p0[27])  << 16);
                a0.y = (unsigned)f2bf(p0[54])     | ((unsigned)f2bf(p0[81])  << 16);
                a0.z = (unsigned)f2bf(p0[108])    | ((unsigned)f2bf(p0[135]) << 16);
                a0.w = (unsigned)f2bf(p0[162])    | ((unsigned)f2bf(p0[189]) << 16);
                a1.x = (unsigned)f2bf(p1[0])      | ((unsigned)f2bf(p1[27])  << 16);
                a1.y = (unsigned)f2bf(p1[54])     | ((unsigned)f2bf(p1[81])  << 16);
                a1.z = (unsigned)f2bf(p1[108])    | ((unsigned)f2bf(p1[135]) << 16);
                a1.w = (unsigned)f2bf(p1[162])    | ((unsigned)f2bf(p1[189]) << 16);
            }
            // B: contiguous 8 bf16 channels
            uint4 b0 = *(const uint4*)(bp0 + kc * 32);
            uint4 b1 = *(const uint4*)(bp1 + kc * 32);

            __syncthreads();
            *(uint4*)&As[row * KP2 + seg * 8] = a0;
            *(uint4*)&As[(row + 64) * KP2 + seg * 8] = a1;
            *(uint4*)&Bs[row * KP2 + seg * 8] = b0;
            *(uint4*)&Bs[(row + 64) * KP2 + seg * 8] = b1;
            __syncthreads();
            s16x8 af[4], bfv[4];
#pragma unroll
            for (int mi = 0; mi < 4; ++mi) af[mi] = *(const s16x8*)&As[(wm + mi * 16 + lid) * KP2 + q * 8];
#pragma unroll
            for (int ni = 0; ni < 4; ++ni) bfv[ni] = *(const s16x8*)&Bs[(wn + ni * 16 + lid) * KP2 + q * 8];
#pragma unroll
            for (int mi = 0; mi < 4; ++mi)
#pragma unroll
                for (int ni = 0; ni < 4; ++ni)
                    acc[mi][ni] = __builtin_amdgcn_mfma_f32_16x16x32_bf16(af[mi], bfv[ni], acc[mi][ni], 0, 0, 0);
        }
    }
#pragma unroll
    for (int mi = 0; mi < 4; ++mi){
        const int mbase = m0 + wm + mi * 16 + q * 4;
        float bv[4];
#pragma unroll
        for (int r2 = 0; r2 < 4; ++r2) bv[r2] = bias[mbase + r2];
#pragma unroll
        for (int ni = 0; ni < 4; ++ni){
            const int n = n0 + wn + ni * 16 + lid;
            if (n < 8640){
                ushort4 o;
                o.x = f2bf(fmaxf(acc[mi][ni][0] + bv[0], 0.f));
                o.y = f2bf(fmaxf(acc[mi][ni][1] + bv[1], 0.f));
                o.z = f2bf(fmaxf(acc[mi][ni][2] + bv[2], 0.f));
                o.w = f2bf(fmaxf(acc[mi][ni][3] + bv[3], 0.f));
                *(ushort4*)(y + (size_t)n * 512 + mbase) = o;
            }
        }
    }
}

// ---------------- GEMM2: conv1b, TAP-MAJOR K, split-K=3 by tap (9 taps each) --------------
__global__ __launch_bounds__(256) void gemm2_kernel(
        const float* __restrict__ w2,  // [256][512][27] fp32 native (oc, ic, tap)
        const u16* __restrict__ y,     // [192][5][3][3][512] bf16
        float* __restrict__ zpart)     // [3][576][256]
{
    __shared__ u16 As[64 * KP2];
    __shared__ u16 Bs[64 * KP2];
    const int tid = threadIdx.x;
    const int m0 = blockIdx.x * 64;
    const int n0 = blockIdx.y * 64;
    const int kz = blockIdx.z;             // taps [kz*9, kz*9+9)
    const int row = tid >> 2, seg = tid & 3;
    const float* arow = w2 + (size_t)(m0 + row) * 13824;
    const int n2 = n0 + row;
    const int fb = n2 / 3, od2 = n2 - fb * 3;
    const u16* bbase = y + (size_t)(fb * 45 + od2 * 9) * 512 + seg * 8;  // + tap*512 + ic
    const int lane = tid & 63, wv = tid >> 6;
    const int wm = (wv & 1) * 32, wn = (wv >> 1) * 32;
    const int lid = lane & 15, q = lane >> 4;
    f32x4 acc[2][2];
#pragma unroll
    for (int i = 0; i < 2; ++i)
#pragma unroll
        for (int j = 0; j < 2; ++j) acc[i][j] = (f32x4){0.f, 0.f, 0.f, 0.f};

    for (int tp = 0; tp < 9; ++tp){
        const int tap = kz * 9 + tp;
        const float* pa = arow + tap;
        const u16* bp = bbase + tap * 512;
        for (int kc = 0; kc < 16; ++kc){
            const int icb = kc * 32 + seg * 8;
            uint4 a;
            {
                const float* p0 = pa + (size_t)icb * 27;
                a.x = (unsigned)f2bf(p0[0])   | ((unsigned)f2bf(p0[27])  << 16);
                a.y = (unsigned)f2bf(p0[54])  | ((unsigned)f2bf(p0[81])  << 16);
                a.z = (unsigned)f2bf(p0[108]) | ((unsigned)f2bf(p0[135]) << 16);
                a.w = (unsigned)f2bf(p0[162]) | ((unsigned)f2bf(p0[189]) << 16);
            }
            uint4 b = *(const uint4*)(bp + kc * 32);

            __syncthreads();
            *(uint4*)&As[row * KP2 + seg * 8] = a;
            *(uint4*)&Bs[row * KP2 + seg * 8] = b;
            __syncthreads();
            s16x8 af[2], bfv[2];
#pragma unroll
            for (int mi = 0; mi < 2; ++mi) af[mi] = *(const s16x8*)&As[(wm + mi * 16 + lid) * KP2 + q * 8];
#pragma unroll
            for (int ni = 0; ni < 2; ++ni) bfv[ni] = *(const s16x8*)&Bs[(wn + ni * 16 + lid) * KP2 + q * 8];
#pragma unroll
            for (int mi = 0; mi < 2; ++mi)
#pragma unroll
                for (int ni = 0; ni < 2; ++ni)
                    acc[mi][ni] = __builtin_amdgcn_mfma_f32_16x16x32_bf16(af[mi], bfv[ni], acc[mi][ni], 0, 0, 0);
        }
    }
#pragma unroll
    for (int mi = 0; mi < 2; ++mi){
        const int mbase = m0 + wm + mi * 16 + q * 4;
#pragma unroll
        for (int ni = 0; ni < 2; ++ni){
            const int n = n0 + wn + ni * 16 + lid;
            float4 o = make_float4(acc[mi][ni][0], acc[mi][ni][1], acc[mi][ni][2], acc[mi][ni][3]);
            *(float4*)(zpart + ((size_t)kz * 576 + n) * 256 + mbase) = o;
        }
    }
}

// ---------------- final: sum split-K + bias + relu + max over D + FC 256->27 (fp32 out) ----
__global__ __launch_bounds__(256) void final_kernel(
        const float* __restrict__ zpart, const float* __restrict__ b2,
        const float* __restrict__ fcw, const float* __restrict__ fcb,
        float* __restrict__ out){
    __shared__ float smv[256];
    const int fb = blockIdx.x, tid = threadIdx.x;
    const float bias = b2[tid];
    float mv = 0.f;   // post-relu values are >= 0
#pragma unroll
    for (int od = 0; od < 3; ++od){
        const int n = fb * 3 + od;
        float s = 0.f;
#pragma unroll
        for (int sp = 0; sp < 3; ++sp) s += zpart[((size_t)sp * 576 + n) * 256 + tid];
        s = fmaxf(s + bias, 0.f);
        mv = fmaxf(mv, s);
    }
    smv[tid] = mv;
    __syncthreads();
    const int wv = tid >> 6, lane = tid & 63;
    for (int cls = wv; cls < 27; cls += 4){
        const float* wrow = fcw + cls * 256;
        float s = 0.f;
#pragma unroll
        for (int j = 0; j < 4; ++j) s += smv[lane + j * 64] * wrow[lane + j * 64];
#pragma unroll
        for (int off = 32; off > 0; off >>= 1) s += __shfl_xor(s, off);
        if (lane == 0) out[fb * 27 + cls] = s + fcb[cls];   // fp32 store (ref output dtype)
    }
}

extern "C" void kernel_launch(void* const* d_in, const int* in_sizes, int n_in,
                              void* d_out, int out_size, void* d_ws, size_t ws_size,
                              hipStream_t stream){
    const float* fmaps = (const float*)d_in[0];
    const float* boxes = (const float*)d_in[1];
    const int*   pid   = (const int*)d_in[2];
    const float* w1    = (const float*)d_in[3];
    const float* b1    = (const float*)d_in[4];
    const float* w2    = (const float*)d_in[5];
    const float* b2    = (const float*)d_in[6];
    const float* fcw   = (const float*)d_in[7];
    const float* fcb   = (const float*)d_in[8];
    float* out = (float*)d_out;

    // ---- workspace layout: TOTAL 14.16 MB ----
    char* ws = (char*)d_ws;
    u16*   rbuf  = (u16*)(ws);                              // 1729*1024*2 = 3,540,992 B
    int*   rowidx= (int*)(ws + 3541248);                    // 3,840 B (padded to 4,096)
    u16*   y     = (u16*)(ws + 3541248 + 4096);             // 8,847,360 B
    float* zpart = (float*)(ws + 3541248 + 4096 + 8847360); // 3*576*256*4 = 1,769,472 B

    hipLaunchKernelGGL(roi_kernel, dim3(1729), dim3(256), 0, stream, fmaps, boxes, rbuf);
    hipLaunchKernelGGL(rowidx_kernel, dim3(4), dim3(256), 0, stream, pid, rowidx);
    hipLaunchKernelGGL(gemm1_kernel, dim3(4, 68), dim3(256), 0, stream, w1, rbuf, rowidx, b1, y);
    hipLaunchKernelGGL(gemm2_kernel, dim3(4, 9, 3), dim3(256), 0, stream, w2, y, zpart);
    hipLaunchKernelGGL(final_kernel, dim3(192), dim3(256), 0, stream, zpart, b2, fcw, fcb, out);
}

// Round 7
// 2244.028 us; speedup vs baseline: 3.1369x; 3.1369x over previous
//
#include <hip/hip_runtime.h>

typedef short s16x8 __attribute__((ext_vector_type(8)));   // 8 bf16 raw bits
typedef float f32x4 __attribute__((ext_vector_type(4)));
typedef unsigned short u16;

__device__ __forceinline__ u16 f2bf(float x){
    unsigned u = __float_as_uint(x);
    unsigned r = u + 0x7fffu + ((u >> 16) & 1u);
    return (u16)(r >> 16);
}

// ---------------- weight prep: in[oc][ic][27] fp32 -> out[oc][tap][C] bf16 -----------------
__global__ void prep_w_kernel(const float* __restrict__ in, u16* __restrict__ out, int icShift){
    extern __shared__ u16 lds[];
    const int C = 1 << icShift;
    const int n = C * 27;
    const int oc = blockIdx.x;
    const float* src = in + (size_t)oc * n;
    for (int i = threadIdx.x; i < n; i += blockDim.x) lds[i] = f2bf(src[i]);
    __syncthreads();
    u16* dst = out + (size_t)oc * n;
    for (int j = threadIdx.x; j < n; j += blockDim.x){
        int tap = j >> icShift;
        int ic  = j & (C - 1);
        dst[j] = lds[ic * 27 + tap];
    }
}

// ---------------- ROI align (fp32 in, bf16 out): rbuf[(f*6+b)*9+sp][1024]; row 1728 = 0 ----
__global__ __launch_bounds__(256) void roi_kernel(const float* __restrict__ fmaps,
                                                  const float* __restrict__ boxes,
                                                  u16* __restrict__ rbuf){
    int blk = blockIdx.x;              // 0..1728 ; 1728 is the zero row
    u16* dst = rbuf + (size_t)blk * 1024;
    if (blk == 1728){
        for (int c = threadIdx.x; c < 1024; c += blockDim.x) dst[c] = 0;
        return;
    }
    int f = blk / 54; int r = blk % 54; int b = r / 9; int sp = r % 9;
    int oh = sp / 3, ow = sp % 3;
    const float* bx = boxes + (f * 6 + b) * 4;
    float x1 = bx[0], y1 = bx[1], x2 = bx[2], y2 = bx[3];
    float bw = fmaxf(x2 - x1, 1.0f) * (1.0f / 3.0f);
    float bh = fmaxf(y2 - y1, 1.0f) * (1.0f / 3.0f);
    int iy0[2], iy1[2], ix0[2], ix1[2];
    float ly[2], lx[2];
#pragma unroll
    for (int s = 0; s < 2; ++s){
        float gy = (float)oh + (s + 0.5f) * 0.5f;
        float ys = y1 + bh * gy;
        float y0f = floorf(ys); y0f = fminf(fmaxf(y0f, 0.f), 13.f);
        ly[s] = fminf(fmaxf(ys - y0f, 0.f), 1.f);
        iy0[s] = (int)y0f; iy1[s] = min(iy0[s] + 1, 13);
        float gx = (float)ow + (s + 0.5f) * 0.5f;
        float xs = x1 + bw * gx;
        float x0f = floorf(xs); x0f = fminf(fmaxf(x0f, 0.f), 13.f);
        lx[s] = fminf(fmaxf(xs - x0f, 0.f), 1.f);
        ix0[s] = (int)x0f; ix1[s] = min(ix0[s] + 1, 13);
    }
    int offs[16]; float wts[16]; int idx = 0;
#pragma unroll
    for (int sy = 0; sy < 2; ++sy)
#pragma unroll
        for (int sx = 0; sx < 2; ++sx){
            float wy1v = ly[sy], wy0v = 1.f - wy1v;
            float wx1v = lx[sx], wx0v = 1.f - wx1v;
            offs[idx] = iy0[sy] * 14 + ix0[sx]; wts[idx] = wy0v * wx0v; idx++;
            offs[idx] = iy0[sy] * 14 + ix1[sx]; wts[idx] = wy0v * wx1v; idx++;
            offs[idx] = iy1[sy] * 14 + ix0[sx]; wts[idx] = wy1v * wx0v; idx++;
            offs[idx] = iy1[sy] * 14 + ix1[sx]; wts[idx] = wy1v * wx1v; idx++;
        }
    const float* fb0 = fmaps + (size_t)f * 1024 * 196;
    for (int c = threadIdx.x; c < 1024; c += blockDim.x){
        const float* fm = fb0 + (size_t)c * 196;
        float acc = 0.f;
#pragma unroll
        for (int i = 0; i < 16; ++i) acc += fm[offs[i]] * wts[i];
        dst[c] = f2bf(acc * 0.25f);
    }
}

// ---------------- rowidx[fb][t] = rbuf row base (r*9) of matched person, or -1 ------------
__global__ void rowidx_kernel(const int* __restrict__ pid, int* __restrict__ rowidx){
    int i = blockIdx.x * blockDim.x + threadIdx.x;   // 960 = 192*5
    if (i >= 960) return;
    int fb = i / 5, t = i % 5;
    int f = fb / 6, b = fb % 6;
    int start = max(f - 2, 0);
    int end = min(start + 4, 31);
    int span = end - start;
    int g = start + (t * span) / 4;
    int p = pid[f * 6 + b];
    int r = -1;
#pragma unroll
    for (int j = 0; j < 6; ++j)
        if (pid[g * 6 + j] == p){ r = (g * 6 + j) * 9; break; }
    rowidx[i] = r;
}

// ---------------- GEMM1: conv1a, 128x128 tile, BK=64, register-prefetch pipeline ----------
#define KP1 72   // LDS row stride (u16): 144 B -> 2-way bank aliasing only (free)

__global__ __launch_bounds__(256) void gemm1_kernel(
        const u16* __restrict__ Wt1,     // [512][27*1024] bf16, k = tap*1024+ic
        const u16* __restrict__ rb,      // [1729][1024] bf16 (row 1728 = 0)
        const int* __restrict__ rowidx,  // [192][5]
        const float* __restrict__ bias,  // [512] fp32
        u16* __restrict__ y)             // [8640][512] channel-last bf16
{
    __shared__ u16 As[128 * KP1];
    __shared__ u16 Bs[128 * KP1];
    __shared__ u16 lut[128 * 27];
    const int tid = threadIdx.x;
    const int m0 = blockIdx.x * 128;
    const int n0 = blockIdx.y * 128;

    // per-block im2col row LUT (1728 = zero row)
    for (int i = tid; i < 128 * 27; i += 256){
        int r = i / 27, tap = i - r * 27;
        int n = n0 + r;
        int v = 1728;
        if (n < 8640){
            int fb = n / 45, rr = n % 45;
            int od = rr / 9, oh = (rr % 9) / 3, ow = rr % 3;
            int kd = tap / 9, kh = (tap % 9) / 3, kw = tap % 3;
            int t = od + kd - 1, h = oh + kh - 1, w = ow + kw - 1;
            if ((unsigned)t < 5u && (unsigned)h < 3u && (unsigned)w < 3u){
                int rbase = rowidx[fb * 5 + t];
                if (rbase >= 0) v = rbase + h * 3 + w;
            }
        }
        lut[i] = (u16)v;
    }
    __syncthreads();

    const int arow = tid >> 1, half = tid & 1;          // 128 rows, 64 B per thread
    const u16* aptr = Wt1 + (size_t)(m0 + arow) * 27648 + half * 32;
    const int lutbase = arow * 27;

    const int lane = tid & 63, wv = tid >> 6;
    const int wm = (wv & 1) * 64, wn = (wv >> 1) * 64;
    const int lid = lane & 15, q = lane >> 4;
    f32x4 acc[4][4];
#pragma unroll
    for (int i = 0; i < 4; ++i)
#pragma unroll
        for (int j = 0; j < 4; ++j) acc[i][j] = (f32x4){0.f, 0.f, 0.f, 0.f};

    uint4 aC[4], bC[4], aN[4], bN[4];
    // initial chunk 0 loads
    {
        const u16* bp = rb + ((size_t)lut[lutbase] << 10) + half * 32;
#pragma unroll
        for (int j = 0; j < 4; ++j){
            aC[j] = *(const uint4*)(aptr + j * 8);
            bC[j] = *(const uint4*)(bp + j * 8);
        }
    }

    for (int kt = 0; kt < 432; ++kt){
        __syncthreads();
        {
            u16* as = &As[arow * KP1 + half * 32];
            u16* bs = &Bs[arow * KP1 + half * 32];
#pragma unroll
            for (int j = 0; j < 4; ++j){
                *(uint4*)(as + j * 8) = aC[j];
                *(uint4*)(bs + j * 8) = bC[j];
            }
        }
        __syncthreads();
        // prefetch next chunk while MFMAs run
        if (kt + 1 < 432){
            const int kn = kt + 1;
            const int tap = kn >> 4;
            const u16* ap = aptr + kn * 64;
            const u16* bp = rb + ((size_t)lut[lutbase + tap] << 10) + (kn & 15) * 64 + half * 32;
#pragma unroll
            for (int j = 0; j < 4; ++j){
                aN[j] = *(const uint4*)(ap + j * 8);
                bN[j] = *(const uint4*)(bp + j * 8);
            }
        }
#pragma unroll
        for (int ks = 0; ks < 2; ++ks){
            s16x8 af[4], bf[4];
#pragma unroll
            for (int mi = 0; mi < 4; ++mi) af[mi] = *(const s16x8*)&As[(wm + mi * 16 + lid) * KP1 + ks * 32 + q * 8];
#pragma unroll
            for (int ni = 0; ni < 4; ++ni) bf[ni] = *(const s16x8*)&Bs[(wn + ni * 16 + lid) * KP1 + ks * 32 + q * 8];
#pragma unroll
            for (int mi = 0; mi < 4; ++mi)
#pragma unroll
                for (int ni = 0; ni < 4; ++ni)
                    acc[mi][ni] = __builtin_amdgcn_mfma_f32_16x16x32_bf16(af[mi], bf[ni], acc[mi][ni], 0, 0, 0);
        }
#pragma unroll
        for (int j = 0; j < 4; ++j){ aC[j] = aN[j]; bC[j] = bN[j]; }
    }
#pragma unroll
    for (int mi = 0; mi < 4; ++mi){
        const int mbase = m0 + wm + mi * 16 + q * 4;
        float bv[4];
#pragma unroll
        for (int r2 = 0; r2 < 4; ++r2) bv[r2] = bias[mbase + r2];
#pragma unroll
        for (int ni = 0; ni < 4; ++ni){
            const int n = n0 + wn + ni * 16 + lid;
            if (n < 8640){
                ushort4 o;
                o.x = f2bf(fmaxf(acc[mi][ni][0] + bv[0], 0.f));
                o.y = f2bf(fmaxf(acc[mi][ni][1] + bv[1], 0.f));
                o.z = f2bf(fmaxf(acc[mi][ni][2] + bv[2], 0.f));
                o.w = f2bf(fmaxf(acc[mi][ni][3] + bv[3], 0.f));
                *(ushort4*)(y + (size_t)n * 512 + mbase) = o;
            }
        }
    }
}

// ---------------- GEMM2: conv1b, 64x64 tile, BK=64, split-K=4, both sides contiguous ------
__global__ __launch_bounds__(256) void gemm2_kernel(
        const u16* __restrict__ Wt2,   // [256][13824] bf16, k = tap*512+ic
        const u16* __restrict__ y,     // [8640][512] bf16; row n=fb*45+od*9+sp
        float* __restrict__ zpart)     // [4][576][256]
{
    __shared__ u16 As[64 * KP1];
    __shared__ u16 Bs[64 * KP1];
    const int tid = threadIdx.x;
    const int m0 = blockIdx.x * 64;
    const int n0 = blockIdx.y * 64;
    const int kz = blockIdx.z;
    const int kbase = kz * 3456;            // 54 chunks of 64
    const int arow = tid >> 2, seg = tid & 3;    // 64 rows, 32 B per thread
    const u16* aptr = Wt2 + (size_t)(m0 + arow) * 13824 + kbase + seg * 16;
    const int n2 = n0 + arow;
    const int fb = n2 / 3, od2 = n2 - fb * 3;
    const u16* bptr = y + (size_t)(fb * 45 + od2 * 9) * 512 + kbase + seg * 16;

    const int lane = tid & 63, wv = tid >> 6;
    const int wm = (wv & 1) * 32, wn = (wv >> 1) * 32;
    const int lid = lane & 15, q = lane >> 4;
    f32x4 acc[2][2];
#pragma unroll
    for (int i = 0; i < 2; ++i)
#pragma unroll
        for (int j = 0; j < 2; ++j) acc[i][j] = (f32x4){0.f, 0.f, 0.f, 0.f};

    uint4 aC[2], bC[2], aN[2], bN[2];
#pragma unroll
    for (int j = 0; j < 2; ++j){
        aC[j] = *(const uint4*)(aptr + j * 8);
        bC[j] = *(const uint4*)(bptr + j * 8);
    }
    for (int kt = 0; kt < 54; ++kt){
        __syncthreads();
        {
            u16* as = &As[arow * KP1 + seg * 16];
            u16* bs = &Bs[arow * KP1 + seg * 16];
#pragma unroll
            for (int j = 0; j < 2; ++j){
                *(uint4*)(as + j * 8) = aC[j];
                *(uint4*)(bs + j * 8) = bC[j];
            }
        }
        __syncthreads();
        if (kt + 1 < 54){
            const u16* ap = aptr + (kt + 1) * 64;
            const u16* bp = bptr + (kt + 1) * 64;
#pragma unroll
            for (int j = 0; j < 2; ++j){
                aN[j] = *(const uint4*)(ap + j * 8);
                bN[j] = *(const uint4*)(bp + j * 8);
            }
        }
#pragma unroll
        for (int ks = 0; ks < 2; ++ks){
            s16x8 af[2], bf[2];
#pragma unroll
            for (int mi = 0; mi < 2; ++mi) af[mi] = *(const s16x8*)&As[(wm + mi * 16 + lid) * KP1 + ks * 32 + q * 8];
#pragma unroll
            for (int ni = 0; ni < 2; ++ni) bf[ni] = *(const s16x8*)&Bs[(wn + ni * 16 + lid) * KP1 + ks * 32 + q * 8];
#pragma unroll
            for (int mi = 0; mi < 2; ++mi)
#pragma unroll
                for (int ni = 0; ni < 2; ++ni)
                    acc[mi][ni] = __builtin_amdgcn_mfma_f32_16x16x32_bf16(af[mi], bf[ni], acc[mi][ni], 0, 0, 0);
        }
#pragma unroll
        for (int j = 0; j < 2; ++j){ aC[j] = aN[j]; bC[j] = bN[j]; }
    }
#pragma unroll
    for (int mi = 0; mi < 2; ++mi){
        const int mbase = m0 + wm + mi * 16 + q * 4;
#pragma unroll
        for (int ni = 0; ni < 2; ++ni){
            const int n = n0 + wn + ni * 16 + lid;
            float4 o = make_float4(acc[mi][ni][0], acc[mi][ni][1], acc[mi][ni][2], acc[mi][ni][3]);
            *(float4*)(zpart + ((size_t)kz * 576 + n) * 256 + mbase) = o;
        }
    }
}

// ---------------- final: sum split-K + bias + relu + max over D + FC 256->27 (fp32 out) ----
__global__ __launch_bounds__(256) void final_kernel(
        const float* __restrict__ zpart, const float* __restrict__ b2,
        const float* __restrict__ fcw, const float* __restrict__ fcb,
        float* __restrict__ out){
    __shared__ float smv[256];
    const int fb = blockIdx.x, tid = threadIdx.x;
    const float bias = b2[tid];
    float mv = 0.f;
#pragma unroll
    for (int od = 0; od < 3; ++od){
        const int n = fb * 3 + od;
        float s = 0.f;
#pragma unroll
        for (int sp = 0; sp < 4; ++sp) s += zpart[((size_t)sp * 576 + n) * 256 + tid];
        s = fmaxf(s + bias, 0.f);
        mv = fmaxf(mv, s);
    }
    smv[tid] = mv;
    __syncthreads();
    const int wv = tid >> 6, lane = tid & 63;
    for (int cls = wv; cls < 27; cls += 4){
        const float* wrow = fcw + cls * 256;
        float s = 0.f;
#pragma unroll
        for (int j = 0; j < 4; ++j) s += smv[lane + j * 64] * wrow[lane + j * 64];
#pragma unroll
        for (int off = 32; off > 0; off >>= 1) s += __shfl_xor(s, off);
        if (lane == 0) out[fb * 27 + cls] = s + fcb[cls];
    }
}

extern "C" void kernel_launch(void* const* d_in, const int* in_sizes, int n_in,
                              void* d_out, int out_size, void* d_ws, size_t ws_size,
                              hipStream_t stream){
    const float* fmaps = (const float*)d_in[0];
    const float* boxes = (const float*)d_in[1];
    const int*   pid   = (const int*)d_in[2];
    const float* w1    = (const float*)d_in[3];
    const float* b1    = (const float*)d_in[4];
    const float* w2    = (const float*)d_in[5];
    const float* b2    = (const float*)d_in[6];
    const float* fcw   = (const float*)d_in[7];
    const float* fcb   = (const float*)d_in[8];
    float* out = (float*)d_out;

    // ---- workspace layout: TOTAL 50,141,440 B (47.8 MB) ----
    char* ws = (char*)d_ws;
    u16*   rbuf  = (u16*)(ws);                                    //  3,541,248
    int*   rowidx= (int*)(ws + 3541248);                          //      4,096
    u16*   y     = (u16*)(ws + 3541248 + 4096);                   //  8,847,360
    float* zpart = (float*)(ws + 3541248 + 4096 + 8847360);       //  2,359,296
    u16*   Wt1   = (u16*)(ws + 3541248 + 4096 + 8847360 + 2359296);           // 28,311,552
    u16*   Wt2   = (u16*)(ws + 3541248 + 4096 + 8847360 + 2359296 + 28311552);//  7,077,888

    hipLaunchKernelGGL(prep_w_kernel, dim3(512), dim3(256), 1024 * 27 * 2, stream, w1, Wt1, 10);
    hipLaunchKernelGGL(prep_w_kernel, dim3(256), dim3(256), 512 * 27 * 2, stream, w2, Wt2, 9);
    hipLaunchKernelGGL(roi_kernel, dim3(1729), dim3(256), 0, stream, fmaps, boxes, rbuf);
    hipLaunchKernelGGL(rowidx_kernel, dim3(4), dim3(256), 0, stream, pid, rowidx);
    hipLaunchKernelGGL(gemm1_kernel, dim3(4, 68), dim3(256), 0, stream, Wt1, rbuf, rowidx, b1, y);
    hipLaunchKernelGGL(gemm2_kernel, dim3(4, 9, 4), dim3(256), 0, stream, Wt2, y, zpart);
    hipLaunchKernelGGL(final_kernel, dim3(192), dim3(256), 0, stream, zpart, b2, fcw, fcb, out);
}

// Round 8
// 629.952 us; speedup vs baseline: 11.1743x; 3.5622x over previous
//
#include <hip/hip_runtime.h>

typedef short s16x8 __attribute__((ext_vector_type(8)));   // 8 bf16 raw bits
typedef float f32x4 __attribute__((ext_vector_type(4)));
typedef unsigned short u16;

__device__ __forceinline__ u16 f2bf(float x){
    unsigned u = __float_as_uint(x);
    unsigned r = u + 0x7fffu + ((u >> 16) & 1u);
    return (u16)(r >> 16);
}
__device__ __forceinline__ float bfhi2f(unsigned v){ return __uint_as_float(v & 0xFFFF0000u); }
__device__ __forceinline__ float bflo2f(unsigned v){ return __uint_as_float(v << 16); }

// ---------------- weight prep: in[oc][ic][27] fp32 -> out[oc][tap][C] bf16 -----------------
__global__ void prep_w_kernel(const float* __restrict__ in, u16* __restrict__ out, int icShift){
    extern __shared__ u16 lds[];
    const int C = 1 << icShift;
    const int n = C * 27;
    const int oc = blockIdx.x;
    const float* src = in + (size_t)oc * n;
    for (int i = threadIdx.x; i < n; i += blockDim.x) lds[i] = f2bf(src[i]);
    __syncthreads();
    u16* dst = out + (size_t)oc * n;
    for (int j = threadIdx.x; j < n; j += blockDim.x){
        int tap = j >> icShift;
        int ic  = j & (C - 1);
        dst[j] = lds[ic * 27 + tap];
    }
}

// ---------------- ROI align (fp32 in, bf16 out): rbuf[(f*6+b)*9+sp][1024]; row 1728 = 0 ----
__global__ __launch_bounds__(256) void roi_kernel(const float* __restrict__ fmaps,
                                                  const float* __restrict__ boxes,
                                                  u16* __restrict__ rbuf){
    int blk = blockIdx.x;              // 0..1728 ; 1728 is the zero row
    u16* dst = rbuf + (size_t)blk * 1024;
    if (blk == 1728){
        for (int c = threadIdx.x; c < 1024; c += blockDim.x) dst[c] = 0;
        return;
    }
    int f = blk / 54; int r = blk % 54; int b = r / 9; int sp = r % 9;
    int oh = sp / 3, ow = sp % 3;
    const float* bx = boxes + (f * 6 + b) * 4;
    float x1 = bx[0], y1 = bx[1], x2 = bx[2], y2 = bx[3];
    float bw = fmaxf(x2 - x1, 1.0f) * (1.0f / 3.0f);
    float bh = fmaxf(y2 - y1, 1.0f) * (1.0f / 3.0f);
    int iy0[2], iy1[2], ix0[2], ix1[2];
    float ly[2], lx[2];
#pragma unroll
    for (int s = 0; s < 2; ++s){
        float gy = (float)oh + (s + 0.5f) * 0.5f;
        float ys = y1 + bh * gy;
        float y0f = floorf(ys); y0f = fminf(fmaxf(y0f, 0.f), 13.f);
        ly[s] = fminf(fmaxf(ys - y0f, 0.f), 1.f);
        iy0[s] = (int)y0f; iy1[s] = min(iy0[s] + 1, 13);
        float gx = (float)ow + (s + 0.5f) * 0.5f;
        float xs = x1 + bw * gx;
        float x0f = floorf(xs); x0f = fminf(fmaxf(x0f, 0.f), 13.f);
        lx[s] = fminf(fmaxf(xs - x0f, 0.f), 1.f);
        ix0[s] = (int)x0f; ix1[s] = min(ix0[s] + 1, 13);
    }
    int offs[16]; float wts[16]; int idx = 0;
#pragma unroll
    for (int sy = 0; sy < 2; ++sy)
#pragma unroll
        for (int sx = 0; sx < 2; ++sx){
            float wy1v = ly[sy], wy0v = 1.f - wy1v;
            float wx1v = lx[sx], wx0v = 1.f - wx1v;
            offs[idx] = iy0[sy] * 14 + ix0[sx]; wts[idx] = wy0v * wx0v; idx++;
            offs[idx] = iy0[sy] * 14 + ix1[sx]; wts[idx] = wy0v * wx1v; idx++;
            offs[idx] = iy1[sy] * 14 + ix0[sx]; wts[idx] = wy1v * wx0v; idx++;
            offs[idx] = iy1[sy] * 14 + ix1[sx]; wts[idx] = wy1v * wx1v; idx++;
        }
    const float* fb0 = fmaps + (size_t)f * 1024 * 196;
    for (int c = threadIdx.x; c < 1024; c += blockDim.x){
        const float* fm = fb0 + (size_t)c * 196;
        float acc = 0.f;
#pragma unroll
        for (int i = 0; i < 16; ++i) acc += fm[offs[i]] * wts[i];
        dst[c] = f2bf(acc * 0.25f);
    }
}

// ---------------- rowidx[fb][t] = rbuf row base (r*9) of matched person, or -1 ------------
__global__ void rowidx_kernel(const int* __restrict__ pid, int* __restrict__ rowidx){
    int i = blockIdx.x * blockDim.x + threadIdx.x;   // 960 = 192*5
    if (i >= 960) return;
    int fb = i / 5, t = i % 5;
    int f = fb / 6, b = fb % 6;
    int start = max(f - 2, 0);
    int end = min(start + 4, 31);
    int span = end - start;
    int g = start + (t * span) / 4;
    int p = pid[f * 6 + b];
    int r = -1;
#pragma unroll
    for (int j = 0; j < 6; ++j)
        if (pid[g * 6 + j] == p){ r = (g * 6 + j) * 9; break; }
    rowidx[i] = r;
}

// ---------------- stage A: per-tap GEMM  P[tap][r][oc] = rbuf[r] . Wt1[oc][tap] -----------
#define KP1 72   // LDS row stride (u16)

__global__ __launch_bounds__(256) void tapgemm_kernel(
        const u16* __restrict__ Wt1,     // [512][27][1024] bf16
        const u16* __restrict__ rb,      // [1729][1024] bf16 (row 1728 = 0)
        u16* __restrict__ P)             // [27][1728][512] bf16
{
    __shared__ u16 As[128 * KP1];
    __shared__ u16 Bs[128 * KP1];
    const int tid = threadIdx.x;
    const int m0 = blockIdx.x * 128;     // oc
    const int n0 = blockIdx.y * 128;     // r
    const int tap = blockIdx.z;

    const int arow = tid >> 1, half = tid & 1;          // 128 rows, 64 B per thread
    const u16* aptr = Wt1 + (size_t)(m0 + arow) * 27648 + tap * 1024 + half * 32;
    const int brow = min(n0 + arow, 1728);              // clamp to zero row
    const u16* bptr = rb + (size_t)brow * 1024 + half * 32;

    const int lane = tid & 63, wv = tid >> 6;
    const int wm = (wv & 1) * 64, wn = (wv >> 1) * 64;
    const int lid = lane & 15, q = lane >> 4;
    f32x4 acc[4][4];
#pragma unroll
    for (int i = 0; i < 4; ++i)
#pragma unroll
        for (int j = 0; j < 4; ++j) acc[i][j] = (f32x4){0.f, 0.f, 0.f, 0.f};

    uint4 aC[4], bC[4], aN[4], bN[4];
#pragma unroll
    for (int j = 0; j < 4; ++j){
        aC[j] = *(const uint4*)(aptr + j * 8);
        bC[j] = *(const uint4*)(bptr + j * 8);
    }
    for (int kt = 0; kt < 16; ++kt){
        __syncthreads();
        {
            u16* as = &As[arow * KP1 + half * 32];
            u16* bs = &Bs[arow * KP1 + half * 32];
#pragma unroll
            for (int j = 0; j < 4; ++j){
                *(uint4*)(as + j * 8) = aC[j];
                *(uint4*)(bs + j * 8) = bC[j];
            }
        }
        __syncthreads();
        if (kt + 1 < 16){
            const u16* ap = aptr + (kt + 1) * 64;
            const u16* bp = bptr + (kt + 1) * 64;
#pragma unroll
            for (int j = 0; j < 4; ++j){
                aN[j] = *(const uint4*)(ap + j * 8);
                bN[j] = *(const uint4*)(bp + j * 8);
            }
        }
#pragma unroll
        for (int ks = 0; ks < 2; ++ks){
            s16x8 af[4], bf[4];
#pragma unroll
            for (int mi = 0; mi < 4; ++mi) af[mi] = *(const s16x8*)&As[(wm + mi * 16 + lid) * KP1 + ks * 32 + q * 8];
#pragma unroll
            for (int ni = 0; ni < 4; ++ni) bf[ni] = *(const s16x8*)&Bs[(wn + ni * 16 + lid) * KP1 + ks * 32 + q * 8];
#pragma unroll
            for (int mi = 0; mi < 4; ++mi)
#pragma unroll
                for (int ni = 0; ni < 4; ++ni)
                    acc[mi][ni] = __builtin_amdgcn_mfma_f32_16x16x32_bf16(af[mi], bf[ni], acc[mi][ni], 0, 0, 0);
        }
#pragma unroll
        for (int j = 0; j < 4; ++j){ aC[j] = aN[j]; bC[j] = bN[j]; }
    }
    u16* Pt = P + (size_t)tap * 1728 * 512;
#pragma unroll
    for (int mi = 0; mi < 4; ++mi){
        const int mbase = m0 + wm + mi * 16 + q * 4;
#pragma unroll
        for (int ni = 0; ni < 4; ++ni){
            const int n = n0 + wn + ni * 16 + lid;
            if (n < 1728){
                ushort4 o;
                o.x = f2bf(acc[mi][ni][0]);
                o.y = f2bf(acc[mi][ni][1]);
                o.z = f2bf(acc[mi][ni][2]);
                o.w = f2bf(acc[mi][ni][3]);
                *(ushort4*)(Pt + (size_t)n * 512 + mbase) = o;
            }
        }
    }
}

// ---------------- stage B: y[n][oc] = relu(b1 + sum_tap P[tap][src(n,tap)][oc]) -----------
__global__ __launch_bounds__(256) void reduce_kernel(
        const unsigned* __restrict__ P32,   // [27][1728][256] (u32 = 2 bf16)
        const int* __restrict__ rowidx,     // [192][5]
        const float* __restrict__ b1,       // [512]
        unsigned* __restrict__ y32)         // [8640][256]
{
    __shared__ int rows[27];
    const int n = blockIdx.x;             // 0..8639
    const int tid = threadIdx.x;
    const int fb = n / 45, rr = n % 45;
    const int od = rr / 9, oh = (rr % 9) / 3, ow = rr % 3;
    if (tid < 27){
        int kd = tid / 9, kh = (tid % 9) / 3, kw = tid % 3;
        int t = od + kd - 1, h = oh + kh - 1, w = ow + kw - 1;
        int row = -1;
        if ((unsigned)t < 5u && (unsigned)h < 3u && (unsigned)w < 3u){
            int rbv = rowidx[fb * 5 + t];
            if (rbv >= 0) row = rbv + h * 3 + w;
        }
        rows[tid] = row;
    }
    __syncthreads();
    float a0 = 0.f, a1 = 0.f;
#pragma unroll
    for (int tap = 0; tap < 27; ++tap){
        int r = rows[tap];
        if (r >= 0){
            unsigned v = P32[((size_t)(tap * 1728 + r) << 8) + tid];
            a0 += bflo2f(v);
            a1 += bfhi2f(v);
        }
    }
    a0 = fmaxf(a0 + b1[tid * 2], 0.f);
    a1 = fmaxf(a1 + b1[tid * 2 + 1], 0.f);
    y32[(size_t)n * 256 + tid] = (unsigned)f2bf(a0) | ((unsigned)f2bf(a1) << 16);
}

// ---------------- GEMM2: conv1b, 64x64 tile, BK=64, split-K=8 -----------------------------
__global__ __launch_bounds__(256) void gemm2_kernel(
        const u16* __restrict__ Wt2,   // [256][13824] bf16, k = tap*512+ic
        const u16* __restrict__ y,     // [8640][512] bf16; row n=fb*45+od*9+sp
        float* __restrict__ zpart)     // [8][576][256]
{
    __shared__ u16 As[64 * KP1];
    __shared__ u16 Bs[64 * KP1];
    const int tid = threadIdx.x;
    const int m0 = blockIdx.x * 64;
    const int n0 = blockIdx.y * 64;
    const int kz = blockIdx.z;
    const int kbase = kz * 1728;            // 27 chunks of 64
    const int arow = tid >> 2, seg = tid & 3;
    const u16* aptr = Wt2 + (size_t)(m0 + arow) * 13824 + kbase + seg * 16;
    const int n2 = n0 + arow;
    const int fb = n2 / 3, od2 = n2 - fb * 3;
    const u16* bptr = y + (size_t)(fb * 45 + od2 * 9) * 512 + kbase + seg * 16;

    const int lane = tid & 63, wv = tid >> 6;
    const int wm = (wv & 1) * 32, wn = (wv >> 1) * 32;
    const int lid = lane & 15, q = lane >> 4;
    f32x4 acc[2][2];
#pragma unroll
    for (int i = 0; i < 2; ++i)
#pragma unroll
        for (int j = 0; j < 2; ++j) acc[i][j] = (f32x4){0.f, 0.f, 0.f, 0.f};

    uint4 aC[2], bC[2], aN[2], bN[2];
#pragma unroll
    for (int j = 0; j < 2; ++j){
        aC[j] = *(const uint4*)(aptr + j * 8);
        bC[j] = *(const uint4*)(bptr + j * 8);
    }
    for (int kt = 0; kt < 27; ++kt){
        __syncthreads();
        {
            u16* as = &As[arow * KP1 + seg * 16];
            u16* bs = &Bs[arow * KP1 + seg * 16];
#pragma unroll
            for (int j = 0; j < 2; ++j){
                *(uint4*)(as + j * 8) = aC[j];
                *(uint4*)(bs + j * 8) = bC[j];
            }
        }
        __syncthreads();
        if (kt + 1 < 27){
            const u16* ap = aptr + (kt + 1) * 64;
            const u16* bp = bptr + (kt + 1) * 64;
#pragma unroll
            for (int j = 0; j < 2; ++j){
                aN[j] = *(const uint4*)(ap + j * 8);
                bN[j] = *(const uint4*)(bp + j * 8);
            }
        }
#pragma unroll
        for (int ks = 0; ks < 2; ++ks){
            s16x8 af[2], bf[2];
#pragma unroll
            for (int mi = 0; mi < 2; ++mi) af[mi] = *(const s16x8*)&As[(wm + mi * 16 + lid) * KP1 + ks * 32 + q * 8];
#pragma unroll
            for (int ni = 0; ni < 2; ++ni) bf[ni] = *(const s16x8*)&Bs[(wn + ni * 16 + lid) * KP1 + ks * 32 + q * 8];
#pragma unroll
            for (int mi = 0; mi < 2; ++mi)
#pragma unroll
                for (int ni = 0; ni < 2; ++ni)
                    acc[mi][ni] = __builtin_amdgcn_mfma_f32_16x16x32_bf16(af[mi], bf[ni], acc[mi][ni], 0, 0, 0);
        }
#pragma unroll
        for (int j = 0; j < 2; ++j){ aC[j] = aN[j]; bC[j] = bN[j]; }
    }
#pragma unroll
    for (int mi = 0; mi < 2; ++mi){
        const int mbase = m0 + wm + mi * 16 + q * 4;
#pragma unroll
        for (int ni = 0; ni < 2; ++ni){
            const int n = n0 + wn + ni * 16 + lid;
            float4 o = make_float4(acc[mi][ni][0], acc[mi][ni][1], acc[mi][ni][2], acc[mi][ni][3]);
            *(float4*)(zpart + ((size_t)kz * 576 + n) * 256 + mbase) = o;
        }
    }
}

// ---------------- final: sum split-K + bias + relu + max over D + FC 256->27 (fp32 out) ----
__global__ __launch_bounds__(256) void final_kernel(
        const float* __restrict__ zpart, const float* __restrict__ b2,
        const float* __restrict__ fcw, const float* __restrict__ fcb,
        float* __restrict__ out){
    __shared__ float smv[256];
    const int fb = blockIdx.x, tid = threadIdx.x;
    const float bias = b2[tid];
    float mv = 0.f;
#pragma unroll
    for (int od = 0; od < 3; ++od){
        const int n = fb * 3 + od;
        float s = 0.f;
#pragma unroll
        for (int sp = 0; sp < 8; ++sp) s += zpart[((size_t)sp * 576 + n) * 256 + tid];
        s = fmaxf(s + bias, 0.f);
        mv = fmaxf(mv, s);
    }
    smv[tid] = mv;
    __syncthreads();
    const int wv = tid >> 6, lane = tid & 63;
    for (int cls = wv; cls < 27; cls += 4){
        const float* wrow = fcw + cls * 256;
        float s = 0.f;
#pragma unroll
        for (int j = 0; j < 4; ++j) s += smv[lane + j * 64] * wrow[lane + j * 64];
#pragma unroll
        for (int off = 32; off > 0; off >>= 1) s += __shfl_xor(s, off);
        if (lane == 0) out[fb * 27 + cls] = s + fcb[cls];
    }
}

extern "C" void kernel_launch(void* const* d_in, const int* in_sizes, int n_in,
                              void* d_out, int out_size, void* d_ws, size_t ws_size,
                              hipStream_t stream){
    const float* fmaps = (const float*)d_in[0];
    const float* boxes = (const float*)d_in[1];
    const int*   pid   = (const int*)d_in[2];
    const float* w1    = (const float*)d_in[3];
    const float* b1    = (const float*)d_in[4];
    const float* w2    = (const float*)d_in[5];
    const float* b2    = (const float*)d_in[6];
    const float* fcw   = (const float*)d_in[7];
    const float* fcb   = (const float*)d_in[8];
    float* out = (float*)d_out;

    // ---- workspace layout: TOTAL 86,710,528 B (86.7 MB) ----
    // [rbuf 3,541,248][rowidx 4,096][Wt1 28,311,552 | alias: y 8,847,360 + zpart 4,718,592]
    // [Wt2 7,077,888][P 47,775,744]
    char* ws = (char*)d_ws;
    u16*   rbuf  = (u16*)(ws);
    int*   rowidx= (int*)(ws + 3541248);
    u16*   Wt1   = (u16*)(ws + 3545344);
    u16*   y     = (u16*)(ws + 3545344);                    // aliases Wt1 (dead after tapgemm)
    float* zpart = (float*)(ws + 3545344 + 8847360);        // also inside Wt1 region
    u16*   Wt2   = (u16*)(ws + 3545344 + 28311552);
    u16*   P     = (u16*)(ws + 3545344 + 28311552 + 7077888);

    hipLaunchKernelGGL(prep_w_kernel, dim3(512), dim3(256), 1024 * 27 * 2, stream, w1, Wt1, 10);
    hipLaunchKernelGGL(prep_w_kernel, dim3(256), dim3(256), 512 * 27 * 2, stream, w2, Wt2, 9);
    hipLaunchKernelGGL(roi_kernel, dim3(1729), dim3(256), 0, stream, fmaps, boxes, rbuf);
    hipLaunchKernelGGL(rowidx_kernel, dim3(4), dim3(256), 0, stream, pid, rowidx);
    hipLaunchKernelGGL(tapgemm_kernel, dim3(4, 14, 27), dim3(256), 0, stream, Wt1, rbuf, P);
    hipLaunchKernelGGL(reduce_kernel, dim3(8640), dim3(256), 0, stream,
                       (const unsigned*)P, rowidx, b1, (unsigned*)y);
    hipLaunchKernelGGL(gemm2_kernel, dim3(4, 9, 8), dim3(256), 0, stream, Wt2, y, zpart);
    hipLaunchKernelGGL(final_kernel, dim3(192), dim3(256), 0, stream, zpart, b2, fcw, fcb, out);
}